// Round 1
// baseline (12849.416 us; speedup 1.0000x reference)
//
#include <hip/hip_runtime.h>
#include <hip/hip_bf16.h>
#include <math.h>

// Problem constants
#define BN   8
#define TT   1024
#define TDIM 256
#define HD   512
#define TSQ  2048
#define SDIM 192

// ws layout (float offsets)
#define OFF_G     0                       // 4*256*512 = 524288
#define OFF_HBIAS (4*256*512)             // 512
#define OFF_HT    (OFF_HBIAS + 1024)      // pad to 525312; 8*2048*512
#define OFF_HS    (OFF_HT + BN*TSQ*HD)

#define SCALE 0.04419417382415922f        // 1/sqrt(512)

// ---------------- G precompute: G[k][ci][h] = sum_co conv_w[ci,co,k]*time_w[co,h]
__global__ void k_G(const float* __restrict__ conv_w, const float* __restrict__ time_w,
                    float* __restrict__ G) {
    const int ci = blockIdx.x & 255;
    const int kk = blockIdx.x >> 8;
    const int tid = threadIdx.x;
    __shared__ float cw[256];
    cw[tid] = conv_w[(ci * 256 + tid) * 4 + kk];
    __syncthreads();
    float a0 = 0.f, a1 = 0.f;
    for (int co = 0; co < 256; ++co) {
        float w = cw[co];
        a0 += w * time_w[co * HD + tid];
        a1 += w * time_w[co * HD + tid + 256];
    }
    G[((kk * 256) + ci) * HD + tid] = a0;
    G[((kk * 256) + ci) * HD + tid + 256] = a1;
}

// ---------------- hbias[h] = time_b[h] + sum_co conv_b[co]*time_w[co,h]
__global__ void k_hbias(const float* __restrict__ conv_b, const float* __restrict__ time_w,
                        const float* __restrict__ time_b, float* __restrict__ hb) {
    const int h = blockIdx.x * 256 + threadIdx.x;
    float a = time_b[h];
    for (int co = 0; co < 256; ++co) a += conv_b[co] * time_w[co * HD + h];
    hb[h] = a;
}

// ---------------- H_time GEMM (fused convT + linear), one parity per blockIdx.z
// even t=2m:  X[m]*G1 + X[m-1]*G3 ; odd t=2m+1: X[m]*G2 + X[m+1]*G0
__global__ void k_htime(const float* __restrict__ X, const float* __restrict__ G,
                        const float* __restrict__ hb, float* __restrict__ HT) {
    const int z  = blockIdx.z;
    const int tid = threadIdx.x;
    __shared__ float As[64][21];
    __shared__ float Bs[16][68];

    const int ridx0 = blockIdx.x * 64;
    const int b  = ridx0 >> 10;
    const int m0 = ridx0 & 1023;
    const int col0 = blockIdx.y * 64;
    const int ga = z ? 2 : 1;
    const int gb = z ? 0 : 3;
    const int dm = z ? 1 : -1;

    const int lr = tid >> 2;            // A row 0..63
    const int lc = (tid & 3) * 4;       // A k-offset
    const int bkr = tid >> 4;           // B row 0..15
    const int bc  = (tid & 15) * 4;     // B col offset
    const int tr = tid >> 4, tc = tid & 15;
    const int r0 = tr * 4, c0 = tc * 4;

    float acc[4][4] = {};

    for (int kk = 0; kk < 512; kk += 16) {
        // A tile
        {
            int k = kk + lc;
            int m = m0 + lr;
            int mm = m, ko = k;
            bool valid = true;
            if (k >= 256) { mm = m + dm; ko = k - 256; valid = (mm >= 0) && (mm < 1024); }
            float4 v = make_float4(0.f, 0.f, 0.f, 0.f);
            if (valid) v = *(const float4*)(X + ((b << 10) + mm) * TDIM + ko);
            As[lr][lc] = v.x; As[lr][lc + 1] = v.y; As[lr][lc + 2] = v.z; As[lr][lc + 3] = v.w;
        }
        // B tile
        {
            int k = kk + bkr;
            const float* Bp = (k < 256) ? (G + (ga * 256 + k) * HD)
                                        : (G + (gb * 256 + (k - 256)) * HD);
            float4 v = *(const float4*)(Bp + col0 + bc);
            *(float4*)&Bs[bkr][bc] = v;
        }
        __syncthreads();
#pragma unroll
        for (int kc = 0; kc < 16; ++kc) {
            float a[4], bb[4];
#pragma unroll
            for (int i = 0; i < 4; ++i) a[i] = As[r0 + i][kc];
#pragma unroll
            for (int j = 0; j < 4; ++j) bb[j] = Bs[kc][c0 + j];
#pragma unroll
            for (int i = 0; i < 4; ++i)
#pragma unroll
                for (int j = 0; j < 4; ++j) acc[i][j] += a[i] * bb[j];
        }
        __syncthreads();
    }
#pragma unroll
    for (int i = 0; i < 4; ++i) {
        int m = m0 + r0 + i;
        int t = 2 * m + z;
        float* op = HT + ((size_t)(b * TSQ) + t) * HD + col0;
#pragma unroll
        for (int j = 0; j < 4; ++j) op[c0 + j] = acc[i][j] + hb[col0 + c0 + j];
    }
}

// ---------------- H_spec GEMM: spec viewed as [B][192][2048] (transposed A)
__global__ void k_hspec(const float* __restrict__ S, const float* __restrict__ spec_w,
                        const float* __restrict__ spec_b, float* __restrict__ HS) {
    const int tid = threadIdx.x;
    __shared__ float As[64][21];   // [t][j]
    __shared__ float Bs[16][68];

    const int row0 = blockIdx.x * 64;
    const int b  = row0 >> 11;
    const int t0 = row0 & 2047;
    const int col0 = blockIdx.y * 64;

    const int jc   = tid >> 4;          // 0..15 (j within chunk)
    const int toff = (tid & 15) * 4;    // t offset
    const int tr = tid >> 4, tc = tid & 15;
    const int r0 = tr * 4, c0 = tc * 4;

    float acc[4][4] = {};

    for (int kk = 0; kk < 192; kk += 16) {
        int j = kk + jc;
        float4 v = *(const float4*)(S + ((size_t)(b * SDIM + j)) * TSQ + t0 + toff);
        As[toff][jc] = v.x; As[toff + 1][jc] = v.y; As[toff + 2][jc] = v.z; As[toff + 3][jc] = v.w;
        float4 w = *(const float4*)(spec_w + j * HD + col0 + tc * 4);
        *(float4*)&Bs[jc][tc * 4] = w;
        __syncthreads();
#pragma unroll
        for (int kc = 0; kc < 16; ++kc) {
            float a[4], bb[4];
#pragma unroll
            for (int i = 0; i < 4; ++i) a[i] = As[r0 + i][kc];
#pragma unroll
            for (int j2 = 0; j2 < 4; ++j2) bb[j2] = Bs[kc][c0 + j2];
#pragma unroll
            for (int i = 0; i < 4; ++i)
#pragma unroll
                for (int j2 = 0; j2 < 4; ++j2) acc[i][j2] += a[i] * bb[j2];
        }
        __syncthreads();
    }
#pragma unroll
    for (int i = 0; i < 4; ++i) {
        float* op = HS + ((size_t)(b * TSQ) + t0 + r0 + i) * HD + col0;
#pragma unroll
        for (int j2 = 0; j2 < 4; ++j2) op[c0 + j2] = acc[i][j2] + spec_b[col0 + c0 + j2];
    }
}

// ---------------- flash attention (fp32), V == K, both passes in one kernel
__global__ __launch_bounds__(256, 2)
void k_flash(const float* __restrict__ HT, const float* __restrict__ HS,
             float* __restrict__ out) {
    const int pass = blockIdx.y;
    const float* Q  = pass ? HS : HT;
    const float* KV = pass ? HT : HS;
    const int ocol  = pass ? HD : 0;
    const int b  = blockIdx.x & 7;           // batch -> XCD locality
    const int qt = blockIdx.x >> 3;
    const int tid = threadIdx.x;
    const int i  = tid >> 3;                 // 0..31 row in tile
    const int hg = tid & 7;
    const int hbase = hg * 64;
    const int t0 = qt * 32;

    __shared__ float KVl[16 * 512];          // swizzled

    // Q row slice into registers
    float4 q[16];
    const float* Qp = Q + ((size_t)(b * TSQ) + t0 + i) * HD + hbase;
#pragma unroll
    for (int c = 0; c < 16; ++c) q[c] = *(const float4*)(Qp + c * 4);

    float4 acc[16];
#pragma unroll
    for (int c = 0; c < 16; ++c) acc[c] = make_float4(0.f, 0.f, 0.f, 0.f);
    float mrow = -1e30f, lrow = 0.f;

    const float* KVb = KV + (size_t)(b * TSQ) * HD;
    float4 nxt[8];
#pragma unroll
    for (int c = 0; c < 8; ++c) nxt[c] = *(const float4*)(KVb + (tid + c * 256) * 4);

    for (int s0 = 0; s0 < TSQ; s0 += 16) {
        __syncthreads();                      // prev compute done with KVl
#pragma unroll
        for (int c = 0; c < 8; ++c) {
            int e4 = tid + c * 256;
            int j = e4 >> 7;
            int g = e4 & 127;
            int gs = g ^ ((g >> 4) & 7);
            *(float4*)&KVl[(j << 9) + (gs << 2)] = nxt[c];
        }
        if (s0 + 16 < TSQ) {
            const float* src = KVb + (size_t)(s0 + 16) * HD;
#pragma unroll
            for (int c = 0; c < 8; ++c) nxt[c] = *(const float4*)(src + (tid + c * 256) * 4);
        }
        __syncthreads();                      // KVl ready

        // scores for this thread's row i, all 16 s
        float p[16];
        float tmax = -1e30f;
#pragma unroll
        for (int j = 0; j < 16; ++j) {
            float pd = 0.f;
#pragma unroll
            for (int c4 = 0; c4 < 16; ++c4) {
                int gs = ((hg << 4) + c4) ^ hg;
                float4 kv = *(const float4*)&KVl[(j << 9) + (gs << 2)];
                pd += q[c4].x * kv.x + q[c4].y * kv.y + q[c4].z * kv.z + q[c4].w * kv.w;
            }
            pd += __shfl_xor(pd, 1, 64);
            pd += __shfl_xor(pd, 2, 64);
            pd += __shfl_xor(pd, 4, 64);
            p[j] = pd * SCALE;
            tmax = fmaxf(tmax, p[j]);
        }
        float mnew = fmaxf(mrow, tmax);
        float alpha = __expf(mrow - mnew);
        float tsum = 0.f;
#pragma unroll
        for (int j = 0; j < 16; ++j) { p[j] = __expf(p[j] - mnew); tsum += p[j]; }
        lrow = lrow * alpha + tsum;
        mrow = mnew;
#pragma unroll
        for (int c = 0; c < 16; ++c) {
            acc[c].x *= alpha; acc[c].y *= alpha; acc[c].z *= alpha; acc[c].w *= alpha;
        }
        // PV (V == K tile)
#pragma unroll
        for (int j = 0; j < 16; ++j) {
            float pj = p[j];
#pragma unroll
            for (int c4 = 0; c4 < 16; ++c4) {
                int gs = ((hg << 4) + c4) ^ hg;
                float4 kv = *(const float4*)&KVl[(j << 9) + (gs << 2)];
                acc[c4].x += pj * kv.x; acc[c4].y += pj * kv.y;
                acc[c4].z += pj * kv.z; acc[c4].w += pj * kv.w;
            }
        }
    }

    const float inv = 1.f / lrow;
    float* op = out + ((size_t)(b * TSQ) + t0 + i) * 1024 + ocol + hbase;
#pragma unroll
    for (int c = 0; c < 16; ++c) {
        float4 v = make_float4(acc[c].x * inv, acc[c].y * inv, acc[c].z * inv, acc[c].w * inv);
        *(float4*)(op + c * 4) = v;
    }
}

extern "C" void kernel_launch(void* const* d_in, const int* in_sizes, int n_in,
                              void* d_out, int out_size, void* d_ws, size_t ws_size,
                              hipStream_t stream) {
    const float* time_features = (const float*)d_in[0];
    const float* spec_features = (const float*)d_in[1];
    const float* conv_w = (const float*)d_in[2];
    const float* conv_b = (const float*)d_in[3];
    const float* time_w = (const float*)d_in[4];
    const float* time_b = (const float*)d_in[5];
    const float* spec_w = (const float*)d_in[6];
    const float* spec_b = (const float*)d_in[7];
    float* out = (float*)d_out;
    float* ws = (float*)d_ws;

    float* G  = ws + OFF_G;
    float* hb = ws + OFF_HBIAS;
    float* HT = ws + OFF_HT;
    float* HS = ws + OFF_HS;

    k_G<<<dim3(1024), 256, 0, stream>>>(conv_w, time_w, G);
    k_hbias<<<dim3(2), 256, 0, stream>>>(conv_b, time_w, time_b, hb);
    k_htime<<<dim3(128, 8, 2), 256, 0, stream>>>(time_features, G, hb, HT);
    k_hspec<<<dim3(256, 8), 256, 0, stream>>>(spec_features, spec_w, spec_b, HS);
    k_flash<<<dim3(512, 2), 256, 0, stream>>>(HT, HS, out);
}

// Round 3
// 631.431 us; speedup vs baseline: 20.3497x; 20.3497x over previous
//
#include <hip/hip_runtime.h>
#include <hip/hip_bf16.h>
#include <math.h>

typedef __attribute__((ext_vector_type(8))) short short8;   // 8 bf16 = 16B
typedef __attribute__((ext_vector_type(4))) float f32x4;

#define BN   8
#define TSQ  2048
#define HD   512
#define TDIM 256
#define SDIM 192
#define SCALE 0.04419417382415922f

// ws layout (bytes)
#define OFFB_G   0
#define OFFB_HB  2097152
#define OFFB_HT  4194304
#define OFFB_HS  20971520

static __device__ __forceinline__ short f2bf(float f) {
    __hip_bfloat16 h = __float2bfloat16(f);
    return *(short*)&h;
}

// ---------------- G precompute: G[k][ci][h] = sum_co conv_w[ci,co,k]*time_w[co,h]
__global__ void k_G(const float* __restrict__ conv_w, const float* __restrict__ time_w,
                    float* __restrict__ G) {
    const int ci = blockIdx.x & 255;
    const int kk = blockIdx.x >> 8;
    const int tid = threadIdx.x;
    __shared__ float cw[256];
    cw[tid] = conv_w[(ci * 256 + tid) * 4 + kk];
    __syncthreads();
    float a0 = 0.f, a1 = 0.f;
    for (int co = 0; co < 256; ++co) {
        float w = cw[co];
        a0 += w * time_w[co * HD + tid];
        a1 += w * time_w[co * HD + tid + 256];
    }
    G[((kk * 256) + ci) * HD + tid] = a0;
    G[((kk * 256) + ci) * HD + tid + 256] = a1;
}

__global__ void k_hbias(const float* __restrict__ conv_b, const float* __restrict__ time_w,
                        const float* __restrict__ time_b, float* __restrict__ hb) {
    const int h = blockIdx.x * 256 + threadIdx.x;
    float a = time_b[h];
    for (int co = 0; co < 256; ++co) a += conv_b[co] * time_w[co * HD + h];
    hb[h] = a;
}

// ---------------- H_time GEMM (fused convT + linear) -> bf16
__global__ void k_htime(const float* __restrict__ X, const float* __restrict__ G,
                        const float* __restrict__ hb, __hip_bfloat16* __restrict__ HT) {
    const int z  = blockIdx.z;
    const int tid = threadIdx.x;
    __shared__ float As[64][21];
    __shared__ float Bs[16][68];

    const int ridx0 = blockIdx.x * 64;
    const int b  = ridx0 >> 10;
    const int m0 = ridx0 & 1023;
    const int col0 = blockIdx.y * 64;
    const int ga = z ? 2 : 1;
    const int gb = z ? 0 : 3;
    const int dm = z ? 1 : -1;

    const int lr = tid >> 2;
    const int lc = (tid & 3) * 4;
    const int bkr = tid >> 4;
    const int bc  = (tid & 15) * 4;
    const int tr = tid >> 4, tc = tid & 15;
    const int r0 = tr * 4, c0 = tc * 4;

    float acc[4][4] = {};

    for (int kk = 0; kk < 512; kk += 16) {
        {
            int k = kk + lc;
            int m = m0 + lr;
            int mm = m, ko = k;
            bool valid = true;
            if (k >= 256) { mm = m + dm; ko = k - 256; valid = (mm >= 0) && (mm < 1024); }
            float4 v = make_float4(0.f, 0.f, 0.f, 0.f);
            if (valid) v = *(const float4*)(X + ((b << 10) + mm) * TDIM + ko);
            As[lr][lc] = v.x; As[lr][lc + 1] = v.y; As[lr][lc + 2] = v.z; As[lr][lc + 3] = v.w;
        }
        {
            int k = kk + bkr;
            const float* Bp = (k < 256) ? (G + (ga * 256 + k) * HD)
                                        : (G + (gb * 256 + (k - 256)) * HD);
            float4 v = *(const float4*)(Bp + col0 + bc);
            *(float4*)&Bs[bkr][bc] = v;
        }
        __syncthreads();
#pragma unroll
        for (int kc = 0; kc < 16; ++kc) {
            float a[4], bb[4];
#pragma unroll
            for (int i = 0; i < 4; ++i) a[i] = As[r0 + i][kc];
#pragma unroll
            for (int j = 0; j < 4; ++j) bb[j] = Bs[kc][c0 + j];
#pragma unroll
            for (int i = 0; i < 4; ++i)
#pragma unroll
                for (int j = 0; j < 4; ++j) acc[i][j] += a[i] * bb[j];
        }
        __syncthreads();
    }
#pragma unroll
    for (int i = 0; i < 4; ++i) {
        int m = m0 + r0 + i;
        int t = 2 * m + z;
        __hip_bfloat16* op = HT + ((size_t)(b * TSQ) + t) * HD + col0;
#pragma unroll
        for (int j = 0; j < 4; ++j) op[c0 + j] = __float2bfloat16(acc[i][j] + hb[col0 + c0 + j]);
    }
}

// ---------------- H_spec GEMM -> bf16
__global__ void k_hspec(const float* __restrict__ S, const float* __restrict__ spec_w,
                        const float* __restrict__ spec_b, __hip_bfloat16* __restrict__ HS) {
    const int tid = threadIdx.x;
    __shared__ float As[64][21];
    __shared__ float Bs[16][68];

    const int row0 = blockIdx.x * 64;
    const int b  = row0 >> 11;
    const int t0 = row0 & 2047;
    const int col0 = blockIdx.y * 64;

    const int jc   = tid >> 4;
    const int toff = (tid & 15) * 4;
    const int tr = tid >> 4, tc = tid & 15;
    const int r0 = tr * 4, c0 = tc * 4;

    float acc[4][4] = {};

    for (int kk = 0; kk < 192; kk += 16) {
        int j = kk + jc;
        float4 v = *(const float4*)(S + ((size_t)(b * SDIM + j)) * TSQ + t0 + toff);
        As[toff][jc] = v.x; As[toff + 1][jc] = v.y; As[toff + 2][jc] = v.z; As[toff + 3][jc] = v.w;
        float4 w = *(const float4*)(spec_w + j * HD + col0 + tc * 4);
        *(float4*)&Bs[jc][tc * 4] = w;
        __syncthreads();
#pragma unroll
        for (int kc = 0; kc < 16; ++kc) {
            float a[4], bb[4];
#pragma unroll
            for (int i = 0; i < 4; ++i) a[i] = As[r0 + i][kc];
#pragma unroll
            for (int j2 = 0; j2 < 4; ++j2) bb[j2] = Bs[kc][c0 + j2];
#pragma unroll
            for (int i = 0; i < 4; ++i)
#pragma unroll
                for (int j2 = 0; j2 < 4; ++j2) acc[i][j2] += a[i] * bb[j2];
        }
        __syncthreads();
    }
#pragma unroll
    for (int i = 0; i < 4; ++i) {
        __hip_bfloat16* op = HS + ((size_t)(b * TSQ) + t0 + r0 + i) * HD + col0;
#pragma unroll
        for (int j2 = 0; j2 < 4; ++j2) op[c0 + j2] = __float2bfloat16(acc[i][j2] + spec_b[col0 + c0 + j2]);
    }
}

// ---------------- MFMA flash attention, V == K, bf16 inputs, fp32 out
// Block: 256 thr (4 waves), 64 q-rows (16/wave), KVB=32 per step.
// Swapped QK^T: S^T = mfma(K, Q) -> lane holds P[q=lane&15][4 s per tile].
#define SM_K  0
#define SM_VT 32768
#define SM_P  (32768 + 40960)
#define SMEM_FLASH (32768 + 40960 + 5120)

__global__ __launch_bounds__(256)
void k_flash(const __hip_bfloat16* __restrict__ HTb, const __hip_bfloat16* __restrict__ HSb,
             float* __restrict__ out) {
    extern __shared__ char smem[];
    ushort* Kl = (ushort*)(smem + SM_K);    // [32][512] swizzled: idx = s*512 + (k ^ ((s&7)<<3))
    ushort* Vt = (ushort*)(smem + SM_VT);   // [512][40]: Vt[h*40+s] = K[s][h]
    ushort* Pl = (ushort*)(smem + SM_P);    // per wave [16][40]

    const int pass = blockIdx.y;
    const __hip_bfloat16* Qg = pass ? HSb : HTb;
    const __hip_bfloat16* Kg = pass ? HTb : HSb;
    const int b  = blockIdx.x & 7;          // batch -> XCD
    const int qt = blockIdx.x >> 3;
    const int tid = threadIdx.x;
    const int w = tid >> 6;
    const int l = tid & 63;
    const int c = l & 15;                   // q (and col) index
    const int g = l >> 4;                   // 4-lane-group

    ushort* Plw = Pl + w * 640;             // 16*40

    // Q fragments: lane holds Q[q = c][k = kk*32 + g*8 .. +7]
    const __hip_bfloat16* Qrow = Qg + ((size_t)(b * TSQ) + qt * 64 + w * 16 + c) * HD;
    short8 qf[16];
#pragma unroll
    for (int kk = 0; kk < 16; ++kk) qf[kk] = *(const short8*)(Qrow + kk * 32 + g * 8);

    f32x4 acc[32];
#pragma unroll
    for (int j = 0; j < 32; ++j) acc[j] = (f32x4){0.f, 0.f, 0.f, 0.f};
    float mrow = -1e30f, lrow = 0.f;

    const __hip_bfloat16* Kb = Kg + (size_t)(b * TSQ) * HD;
    const int ss0 = (tid & 15) * 2;         // staging: s-row pair
    const int hb  = (tid >> 4) * 32;        // staging: h chunk

    for (int s0 = 0; s0 < TSQ; s0 += 32) {
        __syncthreads();
        // ---- stage KV tile: K row-major (swizzled) + V transposed
        {
            const __hip_bfloat16* p0 = Kb + (size_t)(s0 + ss0) * HD + hb;
            const __hip_bfloat16* p1 = p0 + HD;
            short8 ra[4], rb[4];
#pragma unroll
            for (int u = 0; u < 4; ++u) { ra[u] = *(const short8*)(p0 + u * 8); rb[u] = *(const short8*)(p1 + u * 8); }
            const int sA = ss0, sB = ss0 + 1;
#pragma unroll
            for (int u = 0; u < 4; ++u) {
                *(short8*)&Kl[sA * 512 + ((hb + u * 8) ^ ((sA & 7) << 3))] = ra[u];
                *(short8*)&Kl[sB * 512 + ((hb + u * 8) ^ ((sB & 7) << 3))] = rb[u];
            }
#pragma unroll
            for (int u = 0; u < 4; ++u)
#pragma unroll
                for (int e = 0; e < 8; ++e) {
                    int i = u * 8 + e;
                    uint v = (uint)(ushort)ra[u][e] | ((uint)(ushort)rb[u][e] << 16);
                    *(uint*)&Vt[(size_t)(hb + i) * 40 + ss0] = v;
                }
        }
        __syncthreads();

        // ---- QK^T (swapped): S^T = K . Q^T
        f32x4 sv[2];
#pragma unroll
        for (int st = 0; st < 2; ++st) {
            f32x4 s_ = (f32x4){0.f, 0.f, 0.f, 0.f};
            const int srow = st * 16 + c;
            const int swz = (srow & 7) << 3;
            const ushort* kp = Kl + srow * 512;
#pragma unroll
            for (int kk = 0; kk < 16; ++kk) {
                short8 kf = *(const short8*)(kp + ((kk * 32 + g * 8) ^ swz));
                s_ = __builtin_amdgcn_mfma_f32_16x16x32_bf16(kf, qf[kk], s_, 0, 0, 0);
            }
            sv[st] = s_;
        }

        // ---- online softmax (lane owns q = c; s = st*16 + g*4 + r)
        float pv[8];
        float tmax = -1e30f;
#pragma unroll
        for (int st = 0; st < 2; ++st)
#pragma unroll
            for (int r = 0; r < 4; ++r) {
                float x = sv[st][r] * SCALE;
                pv[st * 4 + r] = x;
                tmax = fmaxf(tmax, x);
            }
        tmax = fmaxf(tmax, __shfl_xor(tmax, 16, 64));
        tmax = fmaxf(tmax, __shfl_xor(tmax, 32, 64));
        float mnew = fmaxf(mrow, tmax);
        float alpha = __expf(mrow - mnew);
        float tsum = 0.f;
#pragma unroll
        for (int i = 0; i < 8; ++i) { pv[i] = __expf(pv[i] - mnew); tsum += pv[i]; }
        tsum += __shfl_xor(tsum, 16, 64);
        tsum += __shfl_xor(tsum, 32, 64);
        lrow = lrow * alpha + tsum;
        mrow = mnew;

        // ---- write P (bf16 pairs) to per-wave LDS
#pragma unroll
        for (int st = 0; st < 2; ++st)
#pragma unroll
            for (int pp = 0; pp < 2; ++pp) {
                int s = st * 16 + g * 4 + pp * 2;
                uint v = (uint)(ushort)f2bf(pv[st * 4 + pp * 2]) |
                         ((uint)(ushort)f2bf(pv[st * 4 + pp * 2 + 1]) << 16);
                *(uint*)&Plw[c * 40 + s] = v;
            }

        // ---- rescale accumulator rows (acc row q' = g*4+r)
#pragma unroll
        for (int r = 0; r < 4; ++r) {
            float ar = __shfl(alpha, g * 4 + r, 64);
#pragma unroll
            for (int j = 0; j < 32; ++j) acc[j][r] *= ar;
        }

        // ---- PV: A = P-frag, B = V-frag from Vt
        short8 pa = *(const short8*)(Plw + c * 40 + g * 8);
#pragma unroll
        for (int j = 0; j < 32; ++j) {
            short8 vb = *(const short8*)(Vt + (size_t)(j * 16 + c) * 40 + g * 8);
            acc[j] = __builtin_amdgcn_mfma_f32_16x16x32_bf16(pa, vb, acc[j], 0, 0, 0);
        }
    }

    // ---- epilogue: divide by l per q-row, store fp32
    float linv = 1.f / lrow;
    float* orow = out + ((size_t)(b * TSQ) + qt * 64 + w * 16) * 1024 + (pass ? HD : 0);
#pragma unroll
    for (int r = 0; r < 4; ++r) {
        float inv = __shfl(linv, g * 4 + r, 64);
#pragma unroll
        for (int j = 0; j < 32; ++j)
            orow[(size_t)(g * 4 + r) * 1024 + j * 16 + c] = acc[j][r] * inv;
    }
}

extern "C" void kernel_launch(void* const* d_in, const int* in_sizes, int n_in,
                              void* d_out, int out_size, void* d_ws, size_t ws_size,
                              hipStream_t stream) {
    const float* time_features = (const float*)d_in[0];
    const float* spec_features = (const float*)d_in[1];
    const float* conv_w = (const float*)d_in[2];
    const float* conv_b = (const float*)d_in[3];
    const float* time_w = (const float*)d_in[4];
    const float* time_b = (const float*)d_in[5];
    const float* spec_w = (const float*)d_in[6];
    const float* spec_b = (const float*)d_in[7];
    float* out = (float*)d_out;
    char* ws = (char*)d_ws;

    float* G  = (float*)(ws + OFFB_G);
    float* hb = (float*)(ws + OFFB_HB);
    __hip_bfloat16* HTb = (__hip_bfloat16*)(ws + OFFB_HT);
    __hip_bfloat16* HSb = (__hip_bfloat16*)(ws + OFFB_HS);

    (void)hipFuncSetAttribute((const void*)k_flash, hipFuncAttributeMaxDynamicSharedMemorySize, SMEM_FLASH);

    k_G<<<dim3(1024), 256, 0, stream>>>(conv_w, time_w, G);
    k_hbias<<<dim3(2), 256, 0, stream>>>(conv_b, time_w, time_b, hb);
    k_htime<<<dim3(128, 8, 2), 256, 0, stream>>>(time_features, G, hb, HTb);
    k_hspec<<<dim3(256, 8), 256, 0, stream>>>(spec_features, spec_w, spec_b, HSb);
    k_flash<<<dim3(256, 2), 256, SMEM_FLASH, stream>>>(HTb, HSb, out);
}